// Round 1
// baseline (274.999 us; speedup 1.0000x reference)
//
#include <hip/hip_runtime.h>
#include <hip/hip_bf16.h>

#define B_  32
#define S_  1024
#define E_  768
#define HD_ 64
#define M_  (B_*S_)   // 32768 rows of x

typedef __attribute__((ext_vector_type(8))) short short8;   // 8 bf16 (4 VGPR)
typedef __attribute__((ext_vector_type(4))) float float4v;  // MFMA acc

// fp32 -> bf16 round-to-nearest-even
__device__ __forceinline__ unsigned short f2bf(float x) {
    union { float f; unsigned u; } c; c.f = x;
    unsigned r = (c.u + 0x7FFFu + ((c.u >> 16) & 1u)) >> 16;
    return (unsigned short)r;
}

// load 8 consecutive f32, convert to bf16 short8 (f32-input fallback path)
__device__ __forceinline__ short8 ldcvt_f32(const float* p) {
    float4 a = *(const float4*)p;
    float4 b = *(const float4*)(p + 4);
    short8 r;
    r[0] = (short)f2bf(a.x); r[1] = (short)f2bf(a.y);
    r[2] = (short)f2bf(a.z); r[3] = (short)f2bf(a.w);
    r[4] = (short)f2bf(b.x); r[5] = (short)f2bf(b.y);
    r[6] = (short)f2bf(b.z); r[7] = (short)f2bf(b.w);
    return r;
}

// ---------------------------------------------------------------------------
// RoPE tables (blocks 0..127) + dtype sniffer (block 128). (unchanged)
// ---------------------------------------------------------------------------
__global__ __launch_bounds__(256) void setup_kernel(const unsigned int* __restrict__ xw,
                                                    unsigned int* __restrict__ flag,
                                                    float* __restrict__ cs_t,
                                                    float* __restrict__ sn_t) {
    if (blockIdx.x == 128) {   // dtype sniffer (verified rounds 2-5)
        __shared__ int cnt;
        if (threadIdx.x == 0) cnt = 0;
        __syncthreads();
        unsigned int w = xw[(size_t)threadIdx.x * 33331];
        unsigned int e = (w >> 8) & 0x7F;
        int hit = (e >= 0x3B && e <= 0x40) ? 1 : 0;
        atomicAdd(&cnt, hit);
        __syncthreads();
        if (threadIdx.x == 0) *flag = (cnt > 128) ? 1u : 0u;
        return;
    }
    int idx = blockIdx.x * 256 + threadIdx.x;   // 0 .. 32767
    int pos = idx >> 5;
    int ii  = idx & 31;
    float theta = exp2f(-(float)ii * 0.8304820237218406f);  // log2(10000)/16
    float fr = (float)pos * theta;
    float sn, cs;
    sincosf(fr, &sn, &cs);
    cs_t[idx] = cs;
    sn_t[idx] = sn;
}

// ---------------------------------------------------------------------------
// QKV projection + RoPE, MFMA 16x16x32 bf16 — DIRECT global->VGPR fragments.
// The old LDS staging was a per-lane identity round-trip (write base+lane*16,
// read base+lane*16) gated by a per-chunk __syncthreads (vmcnt(0) drain).
// Now: no LDS, no barriers; each wave loads its own A/B fragments straight
// from global (A redundant 4x across waves -> L1/L2 hit; W is L2-resident).
// Grid 512, block 256 (4 independent waves). Block: 64 rows x 192 cols.
// Wave computes 4 mt x 3 nt (ct = wave*3+nt; q=ct0-3,k=4-7,v=8-11).
// ---------------------------------------------------------------------------
__global__ __launch_bounds__(256, 4) void qkv_mfma_kernel(
    const void* __restrict__ x_, const void* __restrict__ Wq_,
    const void* __restrict__ Wk_, const void* __restrict__ Wv_,
    const unsigned int* __restrict__ flag,
    const float* __restrict__ cs_t, const float* __restrict__ sn_t,
    unsigned short* __restrict__ rq, unsigned short* __restrict__ rk,
    unsigned short* __restrict__ vt)
{
    const bool isb = (*flag != 0);
    const int t    = threadIdx.x;
    const int lane = t & 63;
    const int wave = t >> 6;
    const int quad = lane >> 4;
    const int l15  = lane & 15;
    const int row0 = blockIdx.x * 64;

    // per-lane element offsets (same fragment layout the MFMA consumed via LDS)
    unsigned aoff[4];
    #pragma unroll
    for (int mt = 0; mt < 4; ++mt)
        aoff[mt] = (unsigned)((row0 + mt * 16 + l15) * E_ + quad * 8);

    const void* bptr[3];
    unsigned    boff[3];
    #pragma unroll
    for (int nt = 0; nt < 3; ++nt) {
        int ct  = wave * 3 + nt;
        int reg = ct >> 2;                 // 0=q, 1=k, 2=v
        bptr[nt] = (reg == 0) ? Wq_ : (reg == 1 ? Wk_ : Wv_);
        boff[nt] = (unsigned)(((ct & 3) * 16 + l15) * E_ + quad * 8);
    }

    float4v acc[3][4];
    #pragma unroll
    for (int nt = 0; nt < 3; ++nt)
        #pragma unroll
        for (int mt = 0; mt < 4; ++mt)
            #pragma unroll
            for (int r = 0; r < 4; ++r) acc[nt][mt][r] = 0.f;

    if (isb) {
        const unsigned short* xp = (const unsigned short*)x_;
        #pragma unroll
        for (int c = 0; c < 12; ++c) {
            #pragma unroll
            for (int ks = 0; ks < 2; ++ks) {
                const int k0 = c * 64 + ks * 32;
                short8 af[4], bfr[3];
                #pragma unroll
                for (int mt = 0; mt < 4; ++mt)
                    af[mt] = *(const short8*)(xp + aoff[mt] + k0);
                #pragma unroll
                for (int nt = 0; nt < 3; ++nt)
                    bfr[nt] = *(const short8*)((const unsigned short*)bptr[nt] + boff[nt] + k0);
                #pragma unroll
                for (int nt = 0; nt < 3; ++nt)
                    #pragma unroll
                    for (int mt = 0; mt < 4; ++mt)
                        acc[nt][mt] = __builtin_amdgcn_mfma_f32_16x16x32_bf16(
                            af[mt], bfr[nt], acc[nt][mt], 0, 0, 0);
            }
        }
    } else {
        const float* xp = (const float*)x_;
        #pragma unroll
        for (int c = 0; c < 12; ++c) {
            #pragma unroll
            for (int ks = 0; ks < 2; ++ks) {
                const int k0 = c * 64 + ks * 32;
                short8 af[4], bfr[3];
                #pragma unroll
                for (int mt = 0; mt < 4; ++mt)
                    af[mt] = ldcvt_f32(xp + aoff[mt] + k0);
                #pragma unroll
                for (int nt = 0; nt < 3; ++nt)
                    bfr[nt] = ldcvt_f32((const float*)bptr[nt] + boff[nt] + k0);
                #pragma unroll
                for (int nt = 0; nt < 3; ++nt)
                    #pragma unroll
                    for (int mt = 0; mt < 4; ++mt)
                        acc[nt][mt] = __builtin_amdgcn_mfma_f32_16x16x32_bf16(
                            af[mt], bfr[nt], acc[nt][mt], 0, 0, 0);
            }
        }
    }

    // Epilogue (verified rounds 4-5): C col=l15, row=quad*4+r. RoPE q/k; v transposed.
    const int b      = row0 >> 10;
    const int s_in_b = row0 & (S_ - 1);
    #pragma unroll
    for (int nt = 0; nt < 3; ++nt) {
        int c0 = (wave * 3 + nt) * 16;
        int region = c0 >> 6;          // 0=q, 1=k, 2=v (wave-uniform)
        int d = (c0 & 63) + l15;
        if (region < 2) {
            unsigned short* dst = (region == 0) ? rq : rk;
            int ii = d >> 1;
            #pragma unroll
            for (int mt = 0; mt < 4; ++mt) {
                #pragma unroll
                for (int r = 0; r < 4; ++r) {
                    int row = row0 + mt * 16 + quad * 4 + r;
                    int pos = row & (S_ - 1);
                    float cs = cs_t[pos * 32 + ii];
                    float sn = sn_t[pos * 32 + ii];
                    float val = acc[nt][mt][r];
                    float partner = __shfl_xor(val, 1);   // pair col d^1 = lane^1
                    float res = (d & 1) ? fmaf(val, cs,  partner * sn)
                                        : fmaf(val, cs, -partner * sn);
                    dst[(size_t)row * HD_ + d] = f2bf(res);
                }
            }
        } else {
            #pragma unroll
            for (int mt = 0; mt < 4; ++mt) {
                int sb2 = s_in_b + mt * 16 + quad * 4;
                ushort4 pk;
                pk.x = f2bf(acc[nt][mt][0]);
                pk.y = f2bf(acc[nt][mt][1]);
                pk.z = f2bf(acc[nt][mt][2]);
                pk.w = f2bf(acc[nt][mt][3]);
                *(ushort4*)(vt + ((size_t)(b * 64 + d) * S_ + sb2)) = pk;
            }
        }
    }
}

// ---------------------------------------------------------------------------
// Flash attention, MFMA 16x16x32 bf16, causal, TWO key-tiles per iteration —
// DIRECT global->VGPR K/V fragments (LDS staging removed; it was the same
// identity round-trip). No __syncthreads at all: K/V are L2-resident
// (256 KB per batch), redundant 4x wave reads come from cache. plds is
// per-wave (P transpose), needs no barrier.
// Grid (16, 32), block 256 (4 independent waves, 16 q-rows each).
// ---------------------------------------------------------------------------
__global__ __launch_bounds__(256, 4) void attn_mfma_kernel(
    const unsigned short* __restrict__ rq, const unsigned short* __restrict__ rk,
    const unsigned short* __restrict__ vt, const unsigned int* __restrict__ flag,
    void* __restrict__ out)
{
    __shared__ unsigned short plds[4][16][72];                 // per-wave P buffer

    const bool isb = (*flag != 0);
    const int t    = threadIdx.x;
    const int lane = t & 63;
    const int wave = t >> 6;
    const int quad = lane >> 4;
    const int l15  = lane & 15;
    const int qt   = blockIdx.x;
    const int b    = blockIdx.y;
    const int q0   = qt * 64 + wave * 16;
    const float scale = 0.03608439182435161f;   // 768^-0.5

    // Q A-frags (persistent)
    const unsigned short* qp = rq + ((size_t)(b * S_ + q0 + l15)) * HD_ + quad * 8;
    short8 qf0 = *(const short8*)qp;
    short8 qf1 = *(const short8*)(qp + 32);

    // per-lane fragment bases: K frag(kt,nt,ks) = kq + (kt*64 + nt*16)*HD_ + ks*32
    //                          V frag(kt,nt,ks) = vq + nt*16*S_ + kt*64 + ks*32
    const unsigned short* kq = rk + ((size_t)b * S_ + l15) * HD_ + quad * 8;
    const unsigned short* vq = vt + ((size_t)b * 64 + l15) * S_ + quad * 8;

    float4v o[4];
    float m_[4], l_[4];
    #pragma unroll
    for (int nt = 0; nt < 4; ++nt)
        #pragma unroll
        for (int r = 0; r < 4; ++r) o[nt][r] = 0.f;
    #pragma unroll
    for (int r = 0; r < 4; ++r) { m_[r] = -1e30f; l_[r] = 0.f; }

    const int nIter = (qt + 2) >> 1;

    for (int i = 0; i < nIter; ++i) {
        const int ta = 2 * i;
        const int tb = min(ta + 1, qt);     // dup tail fully masked via logical kg
        const unsigned short* kbase[2] = { kq + (size_t)ta * 64 * HD_,
                                           kq + (size_t)tb * 64 * HD_ };
        const unsigned short* vbase[2] = { vq + ta * 64, vq + tb * 64 };

        // ---- S = Q K^T for both slots ----
        float sc[2][4][4];
        #pragma unroll
        for (int slot = 0; slot < 2; ++slot) {
            #pragma unroll
            for (int nt = 0; nt < 4; ++nt) {
                float4v s;
                #pragma unroll
                for (int r = 0; r < 4; ++r) s[r] = 0.f;
                short8 kf0 = *(const short8*)(kbase[slot] + nt * 16 * HD_);
                short8 kf1 = *(const short8*)(kbase[slot] + nt * 16 * HD_ + 32);
                s = __builtin_amdgcn_mfma_f32_16x16x32_bf16(qf0, kf0, s, 0, 0, 0);
                s = __builtin_amdgcn_mfma_f32_16x16x32_bf16(qf1, kf1, s, 0, 0, 0);
                #pragma unroll
                for (int r = 0; r < 4; ++r) sc[slot][nt][r] = s[r] * scale;
            }
        }

        // ---- causal mask (wave-uniform trigger near diagonal) ----
        if (2 * i + 1 >= qt) {
            #pragma unroll
            for (int slot = 0; slot < 2; ++slot) {
                int ktl = 2 * i + slot;     // LOGICAL tile (dup tail -> all masked)
                #pragma unroll
                for (int nt = 0; nt < 4; ++nt) {
                    int kg = ktl * 64 + nt * 16 + l15;
                    #pragma unroll
                    for (int r = 0; r < 4; ++r) {
                        int qg = q0 + quad * 4 + r;
                        if (kg > qg) sc[slot][nt][r] = -1e30f;
                    }
                }
            }
        }

        // ---- online softmax over 128 keys (16-lane reduce) ----
        float mx[4];
        #pragma unroll
        for (int r = 0; r < 4; ++r) {
            float a0 = fmaxf(fmaxf(sc[0][0][r], sc[0][1][r]), fmaxf(sc[0][2][r], sc[0][3][r]));
            float a1 = fmaxf(fmaxf(sc[1][0][r], sc[1][1][r]), fmaxf(sc[1][2][r], sc[1][3][r]));
            mx[r] = fmaxf(a0, a1);
        }
        #pragma unroll
        for (int st = 1; st < 16; st <<= 1)
            #pragma unroll
            for (int r = 0; r < 4; ++r)
                mx[r] = fmaxf(mx[r], __shfl_xor(mx[r], st));

        float al[4];
        #pragma unroll
        for (int r = 0; r < 4; ++r) {
            float mn = fmaxf(m_[r], mx[r]);
            al[r] = __expf(m_[r] - mn);
            m_[r] = mn;
        }

        float sm[4] = {0.f, 0.f, 0.f, 0.f};
        #pragma unroll
        for (int slot = 0; slot < 2; ++slot)
            #pragma unroll
            for (int nt = 0; nt < 4; ++nt)
                #pragma unroll
                for (int r = 0; r < 4; ++r) {
                    float p = __expf(sc[slot][nt][r] - m_[r]);
                    sc[slot][nt][r] = p;
                    sm[r] += p;
                }
        #pragma unroll
        for (int st = 1; st < 16; st <<= 1)
            #pragma unroll
            for (int r = 0; r < 4; ++r)
                sm[r] += __shfl_xor(sm[r], st);
        #pragma unroll
        for (int r = 0; r < 4; ++r) l_[r] = l_[r] * al[r] + sm[r];

        #pragma unroll
        for (int nt = 0; nt < 4; ++nt)
            #pragma unroll
            for (int r = 0; r < 4; ++r) o[nt][r] *= al[r];

        // ---- per slot: P -> LDS (wave-local) -> A-frag; O += P V ----
        #pragma unroll
        for (int slot = 0; slot < 2; ++slot) {
            #pragma unroll
            for (int nt = 0; nt < 4; ++nt)
                #pragma unroll
                for (int r = 0; r < 4; ++r)
                    plds[wave][quad * 4 + r][nt * 16 + l15] = f2bf(sc[slot][nt][r]);
            short8 pf0 = *(const short8*)&plds[wave][l15][quad * 8];
            short8 pf1 = *(const short8*)&plds[wave][l15][32 + quad * 8];
            #pragma unroll
            for (int nt = 0; nt < 4; ++nt) {
                short8 vf0 = *(const short8*)(vbase[slot] + (size_t)nt * 16 * S_);
                short8 vf1 = *(const short8*)(vbase[slot] + (size_t)nt * 16 * S_ + 32);
                o[nt] = __builtin_amdgcn_mfma_f32_16x16x32_bf16(pf0, vf0, o[nt], 0, 0, 0);
                o[nt] = __builtin_amdgcn_mfma_f32_16x16x32_bf16(pf1, vf1, o[nt], 0, 0, 0);
            }
        }
    }

    // ---- epilogue: normalize, store per dtype ----
    float inv[4];
    #pragma unroll
    for (int r = 0; r < 4; ++r) inv[r] = 1.0f / l_[r];
    if (isb) {
        unsigned short* op = (unsigned short*)out;
        #pragma unroll
        for (int nt = 0; nt < 4; ++nt)
            #pragma unroll
            for (int r = 0; r < 4; ++r) {
                size_t row = (size_t)b * S_ + q0 + quad * 4 + r;
                op[row * HD_ + nt * 16 + l15] = f2bf(o[nt][r] * inv[r]);
            }
    } else {
        float* op = (float*)out;
        #pragma unroll
        for (int nt = 0; nt < 4; ++nt)
            #pragma unroll
            for (int r = 0; r < 4; ++r) {
                size_t row = (size_t)b * S_ + q0 + quad * 4 + r;
                op[row * HD_ + nt * 16 + l15] = o[nt][r] * inv[r];
            }
    }
}

// ---------------------------------------------------------------------------
extern "C" void kernel_launch(void* const* d_in, const int* in_sizes, int n_in,
                              void* d_out, int out_size, void* d_ws, size_t ws_size,
                              hipStream_t stream) {
    const void* x  = d_in[0];
    const void* Wq = d_in[1];
    const void* Wk = d_in[2];
    const void* Wv = d_in[3];

    // ws layout (~12.3 MB; proven available)
    unsigned int* flag = (unsigned int*)d_ws;
    float* cs_t = (float*)d_ws + 64;
    float* sn_t = cs_t + (size_t)S_ * 32;
    unsigned short* rq = (unsigned short*)(sn_t + (size_t)S_ * 32);
    unsigned short* rk = rq + (size_t)M_ * HD_;
    unsigned short* vt = rk + (size_t)M_ * HD_;   // [B][64][S] transposed V

    hipLaunchKernelGGL(setup_kernel, dim3(129), dim3(256), 0, stream,
                       (const unsigned int*)x, flag, cs_t, sn_t);
    hipLaunchKernelGGL(qkv_mfma_kernel, dim3(M_ / 64), dim3(256), 0, stream,
                       x, Wq, Wk, Wv, flag, cs_t, sn_t, rq, rk, vt);
    hipLaunchKernelGGL(attn_mfma_kernel, dim3(S_ / 64, B_), dim3(256), 0, stream,
                       rq, rk, vt, flag, d_out);
}

// Round 2
// 219.559 us; speedup vs baseline: 1.2525x; 1.2525x over previous
//
#include <hip/hip_runtime.h>
#include <hip/hip_bf16.h>

#define B_  32
#define S_  1024
#define E_  768
#define HD_ 64
#define M_  (B_*S_)   // 32768 rows of x

typedef __attribute__((ext_vector_type(8))) short short8;   // 8 bf16 (4 VGPR)
typedef __attribute__((ext_vector_type(4))) float float4v;  // MFMA acc

__device__ __forceinline__ float bf2f(unsigned short u) {
    union { unsigned int i; float f; } c; c.i = ((unsigned int)u) << 16; return c.f;
}
// fp32 -> bf16 round-to-nearest-even
__device__ __forceinline__ unsigned short f2bf(float x) {
    union { float f; unsigned u; } c; c.f = x;
    unsigned r = (c.u + 0x7FFFu + ((c.u >> 16) & 1u)) >> 16;
    return (unsigned short)r;
}

// async global->LDS, 16B per lane; LDS dest = wave-uniform tile base.
__device__ __forceinline__ void gld_lds16(const void* g, void* l) {
    __builtin_amdgcn_global_load_lds(
        (const __attribute__((address_space(1))) unsigned int*)g,
        (__attribute__((address_space(3))) unsigned int*)l,
        16, 0, 0);
}

// ---------------------------------------------------------------------------
// RoPE tables (blocks 0..127) + dtype sniffer (block 128).
// ---------------------------------------------------------------------------
__global__ __launch_bounds__(256) void setup_kernel(const unsigned int* __restrict__ xw,
                                                    unsigned int* __restrict__ flag,
                                                    float* __restrict__ cs_t,
                                                    float* __restrict__ sn_t) {
    if (blockIdx.x == 128) {   // dtype sniffer (verified rounds 2-5)
        __shared__ int cnt;
        if (threadIdx.x == 0) cnt = 0;
        __syncthreads();
        unsigned int w = xw[(size_t)threadIdx.x * 33331];
        unsigned int e = (w >> 8) & 0x7F;
        int hit = (e >= 0x3B && e <= 0x40) ? 1 : 0;
        atomicAdd(&cnt, hit);
        __syncthreads();
        if (threadIdx.x == 0) *flag = (cnt > 128) ? 1u : 0u;
        return;
    }
    int idx = blockIdx.x * 256 + threadIdx.x;   // 0 .. 32767
    int pos = idx >> 5;
    int ii  = idx & 31;
    float theta = exp2f(-(float)ii * 0.8304820237218406f);  // log2(10000)/16
    float fr = (float)pos * theta;
    float sn, cs;
    sincosf(fr, &sn, &cs);
    cs_t[idx] = cs;
    sn_t[idx] = sn;
}

// ---------------------------------------------------------------------------
// QKV projection + RoPE, MFMA 16x16x32 bf16, DOUBLE-BUFFERED gld_lds staging.
// ROUND-2 CHANGE: 8 waves/block (512 thr). qkv total waves were grid-capped
// at 2048 (= 2 waves/SIMD, 25% occ ceiling -> measured 19%); everything was
// latency-bound. Same 64KB LDS (2 blocks/CU) but 512-thr blocks -> 16
// waves/CU = 50% occ cap. Wave w: row-half h=w>>2 (2 mt tiles), col-group
// cw=w&3 (3 ct tiles). Each wave stages 4 of the 32 1KB tiles.
// Tiles 0-7: A(gmt,ks); 8-31: B(ct,ks) ct=0..11 (q0-3,k4-7,v8-11).
// Numerics identical to round-0 (same f2bf, same per-acc MFMA order).
// ---------------------------------------------------------------------------
__global__ __launch_bounds__(512, 4) void qkv_mfma_kernel(
    const void* __restrict__ x_, const void* __restrict__ Wq_,
    const void* __restrict__ Wk_, const void* __restrict__ Wv_,
    const unsigned int* __restrict__ flag,
    const float* __restrict__ cs_t, const float* __restrict__ sn_t,
    unsigned short* __restrict__ rq, unsigned short* __restrict__ rk,
    unsigned short* __restrict__ vt)
{
    __shared__ __align__(16) unsigned short smem[2][32 * 512];   // 64 KB

    const bool isb = (*flag != 0);
    const int t    = threadIdx.x;
    const int lane = t & 63;
    const int wave = t >> 6;        // 0..7
    const int quad = lane >> 4;
    const int l15  = lane & 15;
    const int row0 = blockIdx.x * 64;
    const int h    = wave >> 2;     // row half: mt tiles {h*2, h*2+1}
    const int cw   = wave & 3;      // col group: ct = cw*3 + nt

    // staging descriptors: this wave's 4 tiles (element offsets, u32)
    const void* gbase[4];    // wave-uniform -> SGPR
    unsigned    eo[4];       // per-lane
    int         tidv[4];
    #pragma unroll
    for (int i = 0; i < 4; ++i) {
        int tid = wave * 4 + i;
        tidv[i] = tid;
        if (tid < 8) {                 // A tile: gmt = tid>>1, ks = tid&1
            int gmt = tid >> 1, ks = tid & 1;
            gbase[i] = x_;
            eo[i] = (unsigned)((row0 + gmt * 16 + l15) * E_ + ks * 32 + quad * 8);
        } else {                       // B tile: ct = (tid-8)>>1, ks = (tid-8)&1
            int bi = tid - 8, ct = bi >> 1, ks = bi & 1;
            int reg = ct >> 2;
            gbase[i] = (reg == 0) ? Wq_ : (reg == 1 ? Wk_ : Wv_);
            eo[i] = (unsigned)(((ct & 3) * 16 + l15) * E_ + ks * 32 + quad * 8);
        }
    }

    float4v acc[3][2];
    #pragma unroll
    for (int nt = 0; nt < 3; ++nt)
        #pragma unroll
        for (int mtl = 0; mtl < 2; ++mtl)
            #pragma unroll
            for (int r = 0; r < 4; ++r) acc[nt][mtl][r] = 0.f;

    // ---- stage helper ----
    auto stage = [&](int k0, int bsel) {
        if (isb) {
            #pragma unroll
            for (int i = 0; i < 4; ++i)
                gld_lds16((const unsigned short*)gbase[i] + eo[i] + k0,
                          &smem[bsel][(size_t)tidv[i] * 512]);
        } else {
            #pragma unroll
            for (int i = 0; i < 4; ++i) {
                const float* f = (const float*)gbase[i] + eo[i] + k0;
                float4 a = *(const float4*)f, bq = *(const float4*)(f + 4);
                uint4 w;
                w.x = f2bf(a.x)  | ((unsigned)f2bf(a.y)  << 16);
                w.y = f2bf(a.z)  | ((unsigned)f2bf(a.w)  << 16);
                w.z = f2bf(bq.x) | ((unsigned)f2bf(bq.y) << 16);
                w.w = f2bf(bq.z) | ((unsigned)f2bf(bq.w) << 16);
                *(uint4*)(&smem[bsel][(size_t)tidv[i] * 512] + (size_t)lane * 8) = w;
            }
        }
    };

    stage(0, 0);   // prefetch chunk 0
    int buf = 0;
    for (int c = 0; c < 12; ++c) {
        __syncthreads();                       // drains prefetch of chunk c
        if (c < 11) stage((c + 1) * 64, buf ^ 1);
        const unsigned short* sb = smem[buf];
        #pragma unroll
        for (int ks = 0; ks < 2; ++ks) {
            short8 af[2];
            #pragma unroll
            for (int mtl = 0; mtl < 2; ++mtl)
                af[mtl] = *(const short8*)(sb + (size_t)((h * 2 + mtl) * 2 + ks) * 512 + lane * 8);
            #pragma unroll
            for (int nt = 0; nt < 3; ++nt) {
                int ct = cw * 3 + nt;
                short8 bf = *(const short8*)(sb + (size_t)(8 + ct * 2 + ks) * 512 + lane * 8);
                #pragma unroll
                for (int mtl = 0; mtl < 2; ++mtl)
                    acc[nt][mtl] = __builtin_amdgcn_mfma_f32_16x16x32_bf16(
                        af[mtl], bf, acc[nt][mtl], 0, 0, 0);
            }
        }
        buf ^= 1;
    }

    // Epilogue (verified rounds 4-5): C col=l15, row=quad*4+r. RoPE q/k; v transposed.
    const int b      = row0 >> 10;
    const int s_in_b = row0 & (S_ - 1);
    #pragma unroll
    for (int nt = 0; nt < 3; ++nt) {
        int ct = cw * 3 + nt;
        int c0 = ct * 16;
        int region = c0 >> 6;          // 0=q, 1=k, 2=v (wave-uniform)
        int d = (c0 & 63) + l15;
        if (region < 2) {
            unsigned short* dst = (region == 0) ? rq : rk;
            int ii = d >> 1;
            #pragma unroll
            for (int mtl = 0; mtl < 2; ++mtl) {
                #pragma unroll
                for (int r = 0; r < 4; ++r) {
                    int row = row0 + (h * 2 + mtl) * 16 + quad * 4 + r;
                    int pos = row & (S_ - 1);
                    float cs = cs_t[pos * 32 + ii];
                    float sn = sn_t[pos * 32 + ii];
                    float val = acc[nt][mtl][r];
                    float partner = __shfl_xor(val, 1);   // pair col d^1 = lane^1
                    float res = (d & 1) ? fmaf(val, cs,  partner * sn)
                                        : fmaf(val, cs, -partner * sn);
                    dst[(size_t)row * HD_ + d] = f2bf(res);
                }
            }
        } else {
            #pragma unroll
            for (int mtl = 0; mtl < 2; ++mtl) {
                int sb2 = s_in_b + (h * 2 + mtl) * 16 + quad * 4;
                ushort4 pk;
                pk.x = f2bf(acc[nt][mtl][0]);
                pk.y = f2bf(acc[nt][mtl][1]);
                pk.z = f2bf(acc[nt][mtl][2]);
                pk.w = f2bf(acc[nt][mtl][3]);
                *(ushort4*)(vt + ((size_t)(b * 64 + d) * S_ + sb2)) = pk;
            }
        }
    }
}

// ---------------------------------------------------------------------------
// Flash attention — REVERTED to round-0 proven version (LDS double-buffered
// gld_lds staging, launch_bounds(256,2)). Round-1's direct-load variant with
// launch_bounds(256,4) regressed (~+28us; VGPR cap 128 likely spilled the
// 48-f32 acc state and lost prefetch overlap).
// Grid (16, 32), block 256 (4 waves, 16 q-rows each).
// ---------------------------------------------------------------------------
__global__ __launch_bounds__(256, 2) void attn_mfma_kernel(
    const unsigned short* __restrict__ rq, const unsigned short* __restrict__ rk,
    const unsigned short* __restrict__ vt, const unsigned int* __restrict__ flag,
    void* __restrict__ out)
{
    __shared__ __align__(16) unsigned short kv[2][32 * 512];   // 2 x 32 KB
    __shared__ unsigned short plds[4][16][72];                 // per-wave P buffer

    const bool isb = (*flag != 0);
    const int t    = threadIdx.x;
    const int lane = t & 63;
    const int wave = t >> 6;
    const int quad = lane >> 4;
    const int l15  = lane & 15;
    const int qt   = blockIdx.x;
    const int b    = blockIdx.y;
    const int q0   = qt * 64 + wave * 16;
    const float scale = 0.03608439182435161f;   // 768^-0.5

    // Q A-frags (persistent)
    const unsigned short* qp = rq + ((size_t)(b * S_ + q0 + l15)) * HD_ + quad * 8;
    short8 qf0 = *(const short8*)qp;
    short8 qf1 = *(const short8*)(qp + 32);

    // staging descriptors: this wave's 8 tiles
    const unsigned short* sbase[8];
    unsigned eo[8];
    int      slotv[8], tidv[8], stride[8];
    #pragma unroll
    for (int i = 0; i < 8; ++i) {
        int tid = wave * 8 + i;
        tidv[i] = tid;
        int isV  = tid >> 4;             // 0=K, 1=V
        int rem  = tid & 15;
        int slot = rem >> 3;
        int wi   = rem & 7;
        int nt   = wi >> 1, ks = wi & 1;
        slotv[i] = slot;
        if (!isV) {
            sbase[i]  = rk;
            eo[i]     = (unsigned)((b * S_ + nt * 16 + l15) * HD_ + ks * 32 + quad * 8);
            stride[i] = 64 * HD_;
        } else {
            sbase[i]  = vt;
            eo[i]     = (unsigned)((b * 64 + nt * 16 + l15) * S_ + ks * 32 + quad * 8);
            stride[i] = 64;
        }
    }

    float4v o[4];
    float m_[4], l_[4];
    #pragma unroll
    for (int nt = 0; nt < 4; ++nt)
        #pragma unroll
        for (int r = 0; r < 4; ++r) o[nt][r] = 0.f;
    #pragma unroll
    for (int r = 0; r < 4; ++r) { m_[r] = -1e30f; l_[r] = 0.f; }

    const int nIter = (qt + 2) >> 1;

    auto stage = [&](int it, int bsel) {
        int ta  = 2 * it;
        int tb  = min(ta + 1, qt);
        #pragma unroll
        for (int i = 0; i < 8; ++i) {
            int kt = slotv[i] ? tb : ta;
            gld_lds16(sbase[i] + eo[i] + (size_t)kt * stride[i],
                      &kv[bsel][(size_t)tidv[i] * 512]);
        }
    };

    stage(0, 0);
    int buf = 0;
    for (int i = 0; i < nIter; ++i) {
        __syncthreads();
        if (i + 1 < nIter) stage(i + 1, buf ^ 1);
        const unsigned short* kb = kv[buf];

        // ---- S = Q K^T for both slots ----
        float sc[2][4][4];
        #pragma unroll
        for (int slot = 0; slot < 2; ++slot) {
            #pragma unroll
            for (int nt = 0; nt < 4; ++nt) {
                float4v s;
                #pragma unroll
                for (int r = 0; r < 4; ++r) s[r] = 0.f;
                short8 kf0 = *(const short8*)(kb + (size_t)(slot * 8 + nt * 2 + 0) * 512 + lane * 8);
                short8 kf1 = *(const short8*)(kb + (size_t)(slot * 8 + nt * 2 + 1) * 512 + lane * 8);
                s = __builtin_amdgcn_mfma_f32_16x16x32_bf16(qf0, kf0, s, 0, 0, 0);
                s = __builtin_amdgcn_mfma_f32_16x16x32_bf16(qf1, kf1, s, 0, 0, 0);
                #pragma unroll
                for (int r = 0; r < 4; ++r) sc[slot][nt][r] = s[r] * scale;
            }
        }

        // ---- causal mask (wave-uniform trigger near diagonal) ----
        if (2 * i + 1 >= qt) {
            #pragma unroll
            for (int slot = 0; slot < 2; ++slot) {
                int ktl = 2 * i + slot;     // LOGICAL tile (dup tail -> all masked)
                #pragma unroll
                for (int nt = 0; nt < 4; ++nt) {
                    int kg = ktl * 64 + nt * 16 + l15;
                    #pragma unroll
                    for (int r = 0; r < 4; ++r) {
                        int qg = q0 + quad * 4 + r;
                        if (kg > qg) sc[slot][nt][r] = -1e30f;
                    }
                }
            }
        }

        // ---- online softmax over 128 keys (16-lane reduce) ----
        float mx[4];
        #pragma unroll
        for (int r = 0; r < 4; ++r) {
            float a0 = fmaxf(fmaxf(sc[0][0][r], sc[0][1][r]), fmaxf(sc[0][2][r], sc[0][3][r]));
            float a1 = fmaxf(fmaxf(sc[1][0][r], sc[1][1][r]), fmaxf(sc[1][2][r], sc[1][3][r]));
            mx[r] = fmaxf(a0, a1);
        }
        #pragma unroll
        for (int st = 1; st < 16; st <<= 1)
            #pragma unroll
            for (int r = 0; r < 4; ++r)
                mx[r] = fmaxf(mx[r], __shfl_xor(mx[r], st));

        float al[4];
        #pragma unroll
        for (int r = 0; r < 4; ++r) {
            float mn = fmaxf(m_[r], mx[r]);
            al[r] = __expf(m_[r] - mn);
            m_[r] = mn;
        }

        float sm[4] = {0.f, 0.f, 0.f, 0.f};
        #pragma unroll
        for (int slot = 0; slot < 2; ++slot)
            #pragma unroll
            for (int nt = 0; nt < 4; ++nt)
                #pragma unroll
                for (int r = 0; r < 4; ++r) {
                    float p = __expf(sc[slot][nt][r] - m_[r]);
                    sc[slot][nt][r] = p;
                    sm[r] += p;
                }
        #pragma unroll
        for (int st = 1; st < 16; st <<= 1)
            #pragma unroll
            for (int r = 0; r < 4; ++r)
                sm[r] += __shfl_xor(sm[r], st);
        #pragma unroll
        for (int r = 0; r < 4; ++r) l_[r] = l_[r] * al[r] + sm[r];

        #pragma unroll
        for (int nt = 0; nt < 4; ++nt)
            #pragma unroll
            for (int r = 0; r < 4; ++r) o[nt][r] *= al[r];

        // ---- per slot: P -> LDS -> A-frag; O += P V ----
        #pragma unroll
        for (int slot = 0; slot < 2; ++slot) {
            #pragma unroll
            for (int nt = 0; nt < 4; ++nt)
                #pragma unroll
                for (int r = 0; r < 4; ++r)
                    plds[wave][quad * 4 + r][nt * 16 + l15] = f2bf(sc[slot][nt][r]);
            short8 pf0 = *(const short8*)&plds[wave][l15][quad * 8];
            short8 pf1 = *(const short8*)&plds[wave][l15][32 + quad * 8];
            #pragma unroll
            for (int nt = 0; nt < 4; ++nt) {
                short8 vf0 = *(const short8*)(kb + (size_t)(16 + slot * 8 + nt * 2 + 0) * 512 + lane * 8);
                short8 vf1 = *(const short8*)(kb + (size_t)(16 + slot * 8 + nt * 2 + 1) * 512 + lane * 8);
                o[nt] = __builtin_amdgcn_mfma_f32_16x16x32_bf16(pf0, vf0, o[nt], 0, 0, 0);
                o[nt] = __builtin_amdgcn_mfma_f32_16x16x32_bf16(pf1, vf1, o[nt], 0, 0, 0);
            }
        }
        buf ^= 1;
    }

    // ---- epilogue: normalize, store per dtype ----
    float inv[4];
    #pragma unroll
    for (int r = 0; r < 4; ++r) inv[r] = 1.0f / l_[r];
    if (isb) {
        unsigned short* op = (unsigned short*)out;
        #pragma unroll
        for (int nt = 0; nt < 4; ++nt)
            #pragma unroll
            for (int r = 0; r < 4; ++r) {
                size_t row = (size_t)b * S_ + q0 + quad * 4 + r;
                op[row * HD_ + nt * 16 + l15] = f2bf(o[nt][r] * inv[r]);
            }
    } else {
        float* op = (float*)out;
        #pragma unroll
        for (int nt = 0; nt < 4; ++nt)
            #pragma unroll
            for (int r = 0; r < 4; ++r) {
                size_t row = (size_t)b * S_ + q0 + quad * 4 + r;
                op[row * HD_ + nt * 16 + l15] = o[nt][r] * inv[r];
            }
    }
}

// ---------------------------------------------------------------------------
extern "C" void kernel_launch(void* const* d_in, const int* in_sizes, int n_in,
                              void* d_out, int out_size, void* d_ws, size_t ws_size,
                              hipStream_t stream) {
    const void* x  = d_in[0];
    const void* Wq = d_in[1];
    const void* Wk = d_in[2];
    const void* Wv = d_in[3];

    // ws layout (~12.3 MB; proven available)
    unsigned int* flag = (unsigned int*)d_ws;
    float* cs_t = (float*)d_ws + 64;
    float* sn_t = cs_t + (size_t)S_ * 32;
    unsigned short* rq = (unsigned short*)(sn_t + (size_t)S_ * 32);
    unsigned short* rk = rq + (size_t)M_ * HD_;
    unsigned short* vt = rk + (size_t)M_ * HD_;   // [B][64][S] transposed V

    hipLaunchKernelGGL(setup_kernel, dim3(129), dim3(256), 0, stream,
                       (const unsigned int*)x, flag, cs_t, sn_t);
    hipLaunchKernelGGL(qkv_mfma_kernel, dim3(M_ / 64), dim3(512), 0, stream,
                       x, Wq, Wk, Wv, flag, cs_t, sn_t, rq, rk, vt);
    hipLaunchKernelGGL(attn_mfma_kernel, dim3(S_ / 64, B_), dim3(256), 0, stream,
                       rq, rk, vt, flag, d_out);
}

// Round 3
// 207.519 us; speedup vs baseline: 1.3252x; 1.0580x over previous
//
#include <hip/hip_runtime.h>
#include <hip/hip_bf16.h>

#define B_  32
#define S_  1024
#define E_  768
#define HD_ 64
#define M_  (B_*S_)   // 32768 rows of x

typedef __attribute__((ext_vector_type(8))) short short8;   // 8 bf16 (4 VGPR)
typedef __attribute__((ext_vector_type(4))) float float4v;  // MFMA acc

// fp32 -> bf16 round-to-nearest-even
__device__ __forceinline__ unsigned short f2bf(float x) {
    union { float f; unsigned u; } c; c.f = x;
    unsigned r = (c.u + 0x7FFFu + ((c.u >> 16) & 1u)) >> 16;
    return (unsigned short)r;
}

// async global->LDS, 16B per lane; LDS dest = wave-uniform tile base.
__device__ __forceinline__ void gld_lds16(const void* g, void* l) {
    __builtin_amdgcn_global_load_lds(
        (const __attribute__((address_space(1))) unsigned int*)g,
        (__attribute__((address_space(3))) unsigned int*)l,
        16, 0, 0);
}

// ---------------------------------------------------------------------------
// RoPE tables (blocks 0..127) + dtype sniffer (block 128). (unchanged)
// ---------------------------------------------------------------------------
__global__ __launch_bounds__(256) void setup_kernel(const unsigned int* __restrict__ xw,
                                                    unsigned int* __restrict__ flag,
                                                    float* __restrict__ cs_t,
                                                    float* __restrict__ sn_t) {
    if (blockIdx.x == 128) {   // dtype sniffer (verified rounds 2-5)
        __shared__ int cnt;
        if (threadIdx.x == 0) cnt = 0;
        __syncthreads();
        unsigned int w = xw[(size_t)threadIdx.x * 33331];
        unsigned int e = (w >> 8) & 0x7F;
        int hit = (e >= 0x3B && e <= 0x40) ? 1 : 0;
        atomicAdd(&cnt, hit);
        __syncthreads();
        if (threadIdx.x == 0) *flag = (cnt > 128) ? 1u : 0u;
        return;
    }
    int idx = blockIdx.x * 256 + threadIdx.x;   // 0 .. 32767
    int pos = idx >> 5;
    int ii  = idx & 31;
    float theta = exp2f(-(float)ii * 0.8304820237218406f);  // log2(10000)/16
    float fr = (float)pos * theta;
    float sn, cs;
    sincosf(fr, &sn, &cs);
    cs_t[idx] = cs;
    sn_t[idx] = sn;
}

// ---------------------------------------------------------------------------
// W pre-pack: fragment-tile order Wp[ct(12)][c(12)][ks(2)][lane(64)][8 bf16].
// Tile (ct,c,ks), lane (quad,l15) holds W_sel[(ct&3)*16+l15][c*64+ks*32+quad*8 ..+8]
// where sel = ct>>2 (0=Wq,1=Wk,2=Wv). 288 KB one-time; makes qkv B staging
// perfectly linear gld_lds. Runs after setup (reads flag).
// ---------------------------------------------------------------------------
__global__ __launch_bounds__(256) void wpack_kernel(
    const void* __restrict__ Wq_, const void* __restrict__ Wk_,
    const void* __restrict__ Wv_, const unsigned int* __restrict__ flag,
    unsigned short* __restrict__ wp)
{
    const bool isb = (*flag != 0);
    int gid  = blockIdx.x * 256 + threadIdx.x;   // 0..18431
    int lane = gid & 63;
    int tIdx = gid >> 6;                          // 0..287
    int ct   = tIdx / 24;
    int rem  = tIdx - ct * 24;
    int c    = rem >> 1, ks = rem & 1;
    int quad = lane >> 4, l15 = lane & 15;
    const void* wsel = (ct < 4) ? Wq_ : (ct < 8 ? Wk_ : Wv_);
    int row = (ct & 3) * 16 + l15;
    int col = c * 64 + ks * 32 + quad * 8;
    uint4 w;
    if (isb) {
        w = *(const uint4*)((const unsigned short*)wsel + (size_t)row * E_ + col);
    } else {
        const float* f = (const float*)wsel + (size_t)row * E_ + col;
        float4 a = *(const float4*)f, bq = *(const float4*)(f + 4);
        w.x = f2bf(a.x)  | ((unsigned)f2bf(a.y)  << 16);
        w.y = f2bf(a.z)  | ((unsigned)f2bf(a.w)  << 16);
        w.z = f2bf(bq.x) | ((unsigned)f2bf(bq.y) << 16);
        w.w = f2bf(bq.z) | ((unsigned)f2bf(bq.w) << 16);
    }
    *(uint4*)(wp + (size_t)gid * 8) = w;
}

// ---------------------------------------------------------------------------
// QKV projection + RoPE, MFMA 16x16x32 bf16.
// ROUND-3 CHANGE: all staging made CONTIGUOUS. Old per-chunk fragment tiles
// were 16 scattered 64B segments per gld_lds (rows 1536B apart) -> TA
// serialization, insensitive to occupancy (r1/r2 evidence).
// - A: whole 64x768 tile (96 KB) staged ONCE via 96 linear 1KB gld_lds.
//   Global source fully contiguous; 16B slots XOR-swizzled within each 128B
//   window (pre-swizzled source, linear LDS dest, XOR on ds_read) -> frag
//   reads land 2 lanes/bank (free).
// - B: from wpack'd fragment-order Wp -> linear gld_lds, double-buffered
//   2x24 KB, 12 cheap L2-hot barriers.
// Block 512 thr (8 waves), 64 rows x 192 cols; wave: h=w>>2 (2 mt), cw=w&3
// (3 ct). LDS 144 KB -> 1 block/CU. Grid 512.
// Epilogue writes rq/rk/vt in attn-fragment-PACKED order (same store count).
// ---------------------------------------------------------------------------
__global__ __launch_bounds__(512, 2) void qkv_mfma_kernel(
    const void* __restrict__ x_, const unsigned short* __restrict__ wp,
    const unsigned int* __restrict__ flag,
    const float* __restrict__ cs_t, const float* __restrict__ sn_t,
    unsigned short* __restrict__ rq_p, unsigned short* __restrict__ rk_p,
    unsigned short* __restrict__ vt_p)
{
    __shared__ __align__(16) unsigned short Alds[64 * 768];      // 96 KB
    __shared__ __align__(16) unsigned short Blds[2][24 * 512];   // 2 x 24 KB

    const bool isb = (*flag != 0);
    const int t    = threadIdx.x;
    const int lane = t & 63;
    const int wave = t >> 6;        // 0..7
    const int quad = lane >> 4;
    const int l15  = lane & 15;
    const int row0 = blockIdx.x * 64;
    const int h    = wave >> 2;     // row half: mt tiles {h*2, h*2+1}
    const int cw   = wave & 3;      // col group: ct = cw*3 + nt

    // ---- A staging descriptors: 12 linear 1KB instrs per wave ----
    // LDS layout: row-major [64 rows][1536 B], 16B slot s of each 128B window
    // stored at slot s ^ (row&7). Global source = contiguous bytes with the
    // inverse (same) XOR applied -> address set per instr stays contiguous.
    unsigned eoA[12];                 // per-lane ELEMENT offset in 64x768 tile
    unsigned ldsA[12];                // wave-uniform byte offset of instr dest
    #pragma unroll
    for (int j = 0; j < 12; ++j) {
        unsigned L    = (unsigned)(wave * 12 + j) * 1024u + (unsigned)lane * 16u;
        unsigned row  = L / 1536u;
        unsigned colb = L - row * 1536u;
        unsigned win  = colb >> 7, off = colb & 127u;
        unsigned gcol = (win << 7) | (off ^ ((row & 7u) << 4));
        eoA[j]  = row * 768u + (gcol >> 1);
        ldsA[j] = (unsigned)(wave * 12 + j) * 1024u;
    }

    // ---- A fragment read addrs (bytes): row rl, slot ((ks<<2)|quad)^(rl&7) ----
    unsigned aA[2][2];
    #pragma unroll
    for (int mtl = 0; mtl < 2; ++mtl) {
        unsigned rl = (unsigned)((h * 2 + mtl) * 16 + l15);
        #pragma unroll
        for (int ks = 0; ks < 2; ++ks)
            aA[mtl][ks] = rl * 1536u + 16u * ((((unsigned)ks << 2) | (unsigned)quad) ^ (rl & 7u));
    }

    float4v acc[3][2];
    #pragma unroll
    for (int nt = 0; nt < 3; ++nt)
        #pragma unroll
        for (int mtl = 0; mtl < 2; ++mtl)
            #pragma unroll
            for (int r = 0; r < 4; ++r) acc[nt][mtl][r] = 0.f;

    // ---- B stage: 3 linear tiles per wave per chunk ----
    auto stageB = [&](int c, int bsel) {
        #pragma unroll
        for (int i = 0; i < 3; ++i) {
            int idx = wave * 3 + i;           // 0..23: ct = idx>>1, ks = idx&1
            int ct = idx >> 1, ks = idx & 1;
            gld_lds16(wp + ((size_t)((ct * 12 + c) * 2 + ks)) * 512 + lane * 8,
                      &Blds[bsel][(size_t)idx * 512]);
        }
    };

    // ---- prologue: stage all of A + B chunk 0 ----
    if (isb) {
        const unsigned short* xb = (const unsigned short*)x_ + (size_t)row0 * E_;
        #pragma unroll
        for (int j = 0; j < 12; ++j)
            gld_lds16(xb + eoA[j], (char*)Alds + ldsA[j]);
    } else {
        const float* xb = (const float*)x_ + (size_t)row0 * E_;
        #pragma unroll
        for (int j = 0; j < 12; ++j) {
            const float* f = xb + eoA[j];
            float4 a = *(const float4*)f, bq = *(const float4*)(f + 4);
            uint4 w;
            w.x = f2bf(a.x)  | ((unsigned)f2bf(a.y)  << 16);
            w.y = f2bf(a.z)  | ((unsigned)f2bf(a.w)  << 16);
            w.z = f2bf(bq.x) | ((unsigned)f2bf(bq.y) << 16);
            w.w = f2bf(bq.z) | ((unsigned)f2bf(bq.w) << 16);
            *(uint4*)((char*)Alds + ldsA[j] + (size_t)lane * 16) = w;
        }
    }
    stageB(0, 0);
    __syncthreads();

    int buf = 0;
    for (int c = 0; c < 12; ++c) {
        if (c < 11) stageB(c + 1, buf ^ 1);
        #pragma unroll
        for (int ks = 0; ks < 2; ++ks) {
            short8 af[2];
            af[0] = *(const short8*)((const char*)Alds + aA[0][ks] + c * 128);
            af[1] = *(const short8*)((const char*)Alds + aA[1][ks] + c * 128);
            #pragma unroll
            for (int nt = 0; nt < 3; ++nt) {
                int ct = cw * 3 + nt;
                short8 bf = *(const short8*)(&Blds[buf][(size_t)(ct * 2 + ks) * 512 + lane * 8]);
                acc[nt][0] = __builtin_amdgcn_mfma_f32_16x16x32_bf16(af[0], bf, acc[nt][0], 0, 0, 0);
                acc[nt][1] = __builtin_amdgcn_mfma_f32_16x16x32_bf16(af[1], bf, acc[nt][1], 0, 0, 0);
            }
        }
        __syncthreads();
        buf ^= 1;
    }

    // ---- Epilogue: C col=l15, row=quad*4+r (verified). RoPE q/k; v transposed.
    // Writes go to PACKED fragment-tile layouts:
    //   rq_p/rk_p[b][kt][ntq][ksq][lane'][8]: rows kt*64+ntq*16+l15', cols ksq*32+quadq*8..
    //   vt_p    [b][kt][ntv][ksv][lane'][8]: head-row ntv*16+l15v, seq cols ...
    const int b      = row0 >> 10;
    const int s_in_b = row0 & (S_ - 1);
    #pragma unroll
    for (int nt = 0; nt < 3; ++nt) {
        int ct = cw * 3 + nt;
        int region = ct >> 2;          // 0=q, 1=k, 2=v (wave-uniform)
        int d = (ct & 3) * 16 + l15;
        if (region < 2) {
            unsigned short* dst = (region == 0) ? rq_p : rk_p;
            int ii = d >> 1;
            int ksq = d >> 5, quadq = (d >> 3) & 3, e = d & 7;
            #pragma unroll
            for (int mtl = 0; mtl < 2; ++mtl) {
                #pragma unroll
                for (int r = 0; r < 4; ++r) {
                    int row = row0 + (h * 2 + mtl) * 16 + quad * 4 + r;
                    int pos = row & (S_ - 1);
                    float cs = cs_t[pos * 32 + ii];
                    float sn = sn_t[pos * 32 + ii];
                    float val = acc[nt][mtl][r];
                    float partner = __shfl_xor(val, 1);   // pair col d^1 = lane^1
                    float res = (d & 1) ? fmaf(val, cs,  partner * sn)
                                        : fmaf(val, cs, -partner * sn);
                    int kt = pos >> 6, ntq = (pos >> 4) & 3, l15q = pos & 15;
                    size_t idx = ((((size_t)(b * 16 + kt) * 4 + ntq) * 2 + ksq) * 64
                                  + quadq * 16 + l15q) * 8 + e;
                    dst[idx] = f2bf(res);
                }
            }
        } else {
            int ntv = ct & 3;          // d = ntv*16 + l15
            #pragma unroll
            for (int mtl = 0; mtl < 2; ++mtl) {
                int sb2 = s_in_b + (h * 2 + mtl) * 16 + quad * 4;
                int kt = sb2 >> 6, ksv = (sb2 >> 5) & 1, quadv = (sb2 >> 3) & 3, e0 = sb2 & 7;
                ushort4 pk;
                pk.x = f2bf(acc[nt][mtl][0]);
                pk.y = f2bf(acc[nt][mtl][1]);
                pk.z = f2bf(acc[nt][mtl][2]);
                pk.w = f2bf(acc[nt][mtl][3]);
                size_t idx = ((((size_t)(b * 16 + kt) * 4 + ntv) * 2 + ksv) * 64
                              + quadv * 16 + l15) * 8 + e0;
                *(ushort4*)(vt_p + idx) = pk;
            }
        }
    }
}

// ---------------------------------------------------------------------------
// Flash attention — round-0 proven compute, staging from PACKED layouts:
// every gld_lds16 is now a fully LINEAR 1KB tile read (was 16 scattered 64B
// segments). kv LDS layout, softmax, masks, epilogue byte-identical to r0.
// Grid (16, 32), block 256 (4 waves, 16 q-rows each).
// ---------------------------------------------------------------------------
__global__ __launch_bounds__(256, 2) void attn_mfma_kernel(
    const unsigned short* __restrict__ rq_p, const unsigned short* __restrict__ rk_p,
    const unsigned short* __restrict__ vt_p, const unsigned int* __restrict__ flag,
    void* __restrict__ out)
{
    __shared__ __align__(16) unsigned short kv[2][32 * 512];   // 2 x 32 KB
    __shared__ unsigned short plds[4][16][72];                 // per-wave P buffer

    const bool isb = (*flag != 0);
    const int t    = threadIdx.x;
    const int lane = t & 63;
    const int wave = t >> 6;
    const int quad = lane >> 4;
    const int l15  = lane & 15;
    const int qt   = blockIdx.x;
    const int b    = blockIdx.y;
    const int q0   = qt * 64 + wave * 16;
    const float scale = 0.03608439182435161f;   // 768^-0.5

    // Q A-frags from packed tile (b, kt=qt, nt=wave)
    const unsigned short* qb = rq_p + ((size_t)((b * 16 + qt) * 4 + wave) * 2) * 512;
    short8 qf0 = *(const short8*)(qb + lane * 8);
    short8 qf1 = *(const short8*)(qb + 512 + lane * 8);

    // staging descriptors: this wave's 8 tiles, all linear
    const unsigned short* sbase[8];
    unsigned eo[8];
    int      slotv[8], tidv[8];
    #pragma unroll
    for (int i = 0; i < 8; ++i) {
        int tid = wave * 8 + i;
        tidv[i] = tid;
        int isV  = tid >> 4;             // 0=K, 1=V
        int rem  = tid & 15;
        int slot = rem >> 3;
        int wi   = rem & 7;
        int nt   = wi >> 1, ks = wi & 1;
        slotv[i] = slot;
        sbase[i] = isV ? vt_p : rk_p;
        eo[i]    = (unsigned)(((b * 64 + nt) * 2 + ks) * 512 + lane * 8);  // kt=0 base
    }

    float4v o[4];
    float m_[4], l_[4];
    #pragma unroll
    for (int nt = 0; nt < 4; ++nt)
        #pragma unroll
        for (int r = 0; r < 4; ++r) o[nt][r] = 0.f;
    #pragma unroll
    for (int r = 0; r < 4; ++r) { m_[r] = -1e30f; l_[r] = 0.f; }

    const int nIter = (qt + 2) >> 1;

    auto stage = [&](int it, int bsel) {
        int ta  = 2 * it;
        int tb  = min(ta + 1, qt);
        #pragma unroll
        for (int i = 0; i < 8; ++i) {
            int kt = slotv[i] ? tb : ta;
            gld_lds16(sbase[i] + eo[i] + (size_t)kt * 4096,   // kt stride = 4*2*512
                      &kv[bsel][(size_t)tidv[i] * 512]);
        }
    };

    stage(0, 0);
    int buf = 0;
    for (int i = 0; i < nIter; ++i) {
        __syncthreads();
        if (i + 1 < nIter) stage(i + 1, buf ^ 1);
        const unsigned short* kb = kv[buf];

        // ---- S = Q K^T for both slots ----
        float sc[2][4][4];
        #pragma unroll
        for (int slot = 0; slot < 2; ++slot) {
            #pragma unroll
            for (int nt = 0; nt < 4; ++nt) {
                float4v s;
                #pragma unroll
                for (int r = 0; r < 4; ++r) s[r] = 0.f;
                short8 kf0 = *(const short8*)(kb + (size_t)(slot * 8 + nt * 2 + 0) * 512 + lane * 8);
                short8 kf1 = *(const short8*)(kb + (size_t)(slot * 8 + nt * 2 + 1) * 512 + lane * 8);
                s = __builtin_amdgcn_mfma_f32_16x16x32_bf16(qf0, kf0, s, 0, 0, 0);
                s = __builtin_amdgcn_mfma_f32_16x16x32_bf16(qf1, kf1, s, 0, 0, 0);
                #pragma unroll
                for (int r = 0; r < 4; ++r) sc[slot][nt][r] = s[r] * scale;
            }
        }

        // ---- causal mask (wave-uniform trigger near diagonal) ----
        if (2 * i + 1 >= qt) {
            #pragma unroll
            for (int slot = 0; slot < 2; ++slot) {
                int ktl = 2 * i + slot;     // LOGICAL tile (dup tail -> all masked)
                #pragma unroll
                for (int nt = 0; nt < 4; ++nt) {
                    int kg = ktl * 64 + nt * 16 + l15;
                    #pragma unroll
                    for (int r = 0; r < 4; ++r) {
                        int qg = q0 + quad * 4 + r;
                        if (kg > qg) sc[slot][nt][r] = -1e30f;
                    }
                }
            }
        }

        // ---- online softmax over 128 keys (16-lane reduce) ----
        float mx[4];
        #pragma unroll
        for (int r = 0; r < 4; ++r) {
            float a0 = fmaxf(fmaxf(sc[0][0][r], sc[0][1][r]), fmaxf(sc[0][2][r], sc[0][3][r]));
            float a1 = fmaxf(fmaxf(sc[1][0][r], sc[1][1][r]), fmaxf(sc[1][2][r], sc[1][3][r]));
            mx[r] = fmaxf(a0, a1);
        }
        #pragma unroll
        for (int st = 1; st < 16; st <<= 1)
            #pragma unroll
            for (int r = 0; r < 4; ++r)
                mx[r] = fmaxf(mx[r], __shfl_xor(mx[r], st));

        float al[4];
        #pragma unroll
        for (int r = 0; r < 4; ++r) {
            float mn = fmaxf(m_[r], mx[r]);
            al[r] = __expf(m_[r] - mn);
            m_[r] = mn;
        }

        float sm[4] = {0.f, 0.f, 0.f, 0.f};
        #pragma unroll
        for (int slot = 0; slot < 2; ++slot)
            #pragma unroll
            for (int nt = 0; nt < 4; ++nt)
                #pragma unroll
                for (int r = 0; r < 4; ++r) {
                    float p = __expf(sc[slot][nt][r] - m_[r]);
                    sc[slot][nt][r] = p;
                    sm[r] += p;
                }
        #pragma unroll
        for (int st = 1; st < 16; st <<= 1)
            #pragma unroll
            for (int r = 0; r < 4; ++r)
                sm[r] += __shfl_xor(sm[r], st);
        #pragma unroll
        for (int r = 0; r < 4; ++r) l_[r] = l_[r] * al[r] + sm[r];

        #pragma unroll
        for (int nt = 0; nt < 4; ++nt)
            #pragma unroll
            for (int r = 0; r < 4; ++r) o[nt][r] *= al[r];

        // ---- per slot: P -> LDS -> A-frag; O += P V ----
        #pragma unroll
        for (int slot = 0; slot < 2; ++slot) {
            #pragma unroll
            for (int nt = 0; nt < 4; ++nt)
                #pragma unroll
                for (int r = 0; r < 4; ++r)
                    plds[wave][quad * 4 + r][nt * 16 + l15] = f2bf(sc[slot][nt][r]);
            short8 pf0 = *(const short8*)&plds[wave][l15][quad * 8];
            short8 pf1 = *(const short8*)&plds[wave][l15][32 + quad * 8];
            #pragma unroll
            for (int nt = 0; nt < 4; ++nt) {
                short8 vf0 = *(const short8*)(kb + (size_t)(16 + slot * 8 + nt * 2 + 0) * 512 + lane * 8);
                short8 vf1 = *(const short8*)(kb + (size_t)(16 + slot * 8 + nt * 2 + 1) * 512 + lane * 8);
                o[nt] = __builtin_amdgcn_mfma_f32_16x16x32_bf16(pf0, vf0, o[nt], 0, 0, 0);
                o[nt] = __builtin_amdgcn_mfma_f32_16x16x32_bf16(pf1, vf1, o[nt], 0, 0, 0);
            }
        }
        buf ^= 1;
    }

    // ---- epilogue: normalize, store per dtype ----
    float inv[4];
    #pragma unroll
    for (int r = 0; r < 4; ++r) inv[r] = 1.0f / l_[r];
    if (isb) {
        unsigned short* op = (unsigned short*)out;
        #pragma unroll
        for (int nt = 0; nt < 4; ++nt)
            #pragma unroll
            for (int r = 0; r < 4; ++r) {
                size_t row = (size_t)b * S_ + q0 + quad * 4 + r;
                op[row * HD_ + nt * 16 + l15] = f2bf(o[nt][r] * inv[r]);
            }
    } else {
        float* op = (float*)out;
        #pragma unroll
        for (int nt = 0; nt < 4; ++nt)
            #pragma unroll
            for (int r = 0; r < 4; ++r) {
                size_t row = (size_t)b * S_ + q0 + quad * 4 + r;
                op[row * HD_ + nt * 16 + l15] = o[nt][r] * inv[r];
            }
    }
}

// ---------------------------------------------------------------------------
extern "C" void kernel_launch(void* const* d_in, const int* in_sizes, int n_in,
                              void* d_out, int out_size, void* d_ws, size_t ws_size,
                              hipStream_t stream) {
    const void* x  = d_in[0];
    const void* Wq = d_in[1];
    const void* Wk = d_in[2];
    const void* Wv = d_in[3];

    // ws layout (~12.9 MB)
    unsigned int* flag = (unsigned int*)d_ws;
    float* cs_t = (float*)d_ws + 64;
    float* sn_t = cs_t + (size_t)S_ * 32;
    unsigned short* wp   = (unsigned short*)(sn_t + (size_t)S_ * 32);  // 288 tiles
    unsigned short* rq_p = wp + (size_t)288 * 512;
    unsigned short* rk_p = rq_p + (size_t)M_ * HD_;
    unsigned short* vt_p = rk_p + (size_t)M_ * HD_;

    hipLaunchKernelGGL(setup_kernel, dim3(129), dim3(256), 0, stream,
                       (const unsigned int*)x, flag, cs_t, sn_t);
    hipLaunchKernelGGL(wpack_kernel, dim3(72), dim3(256), 0, stream,
                       Wq, Wk, Wv, flag, wp);
    hipLaunchKernelGGL(qkv_mfma_kernel, dim3(M_ / 64), dim3(512), 0, stream,
                       x, wp, flag, cs_t, sn_t, rq_p, rk_p, vt_p);
    hipLaunchKernelGGL(attn_mfma_kernel, dim3(S_ / 64, B_), dim3(256), 0, stream,
                       rq_p, rk_p, vt_p, flag, d_out);
}